// Round 1
// baseline (155.445 us; speedup 1.0000x reference)
//
#include <hip/hip_runtime.h>

#define NPTS   65536
#define KNN    8
#define CDIM   64
#define SHB    9
#define NCODES 8192

__global__ __launch_bounds__(256) void shcode_kernel(
    const float* __restrict__ qp,     // (N,3) query points
    const float* __restrict__ vd,     // (N,3) viewdirs (normalized)
    const float* __restrict__ cpos,   // (8192,3) code positions
    const float* __restrict__ codes,  // (8192,64)
    const float* __restrict__ shc,    // (8192,576) = (8192, 64*9)
    const int*   __restrict__ knn,    // (N,8)
    float* __restrict__ out)          // [0..N*64): query_codes, [N*64..2N*64): query_sh_codes
{
    const int wid  = threadIdx.x >> 6;     // wave id in block (4 waves/block)
    const int lane = threadIdx.x & 63;     // code dim owned by this lane
    const int n    = blockIdx.x * 4 + wid; // point id (one wave per point)

    // --- SH basis from viewdir (wave-uniform; same-address loads broadcast) ---
    const float x = vd[n * 3 + 0];
    const float y = vd[n * 3 + 1];
    const float z = vd[n * 3 + 2];
    const float xx = x * x, yy = y * y, zz = z * z;
    const float sm0 = 0.28209479177387814f;
    const float sm1 = -0.4886025119029199f * y;
    const float sm2 =  0.4886025119029199f * z;
    const float sm3 = -0.4886025119029199f * x;
    const float sm4 =  1.0925484305920792f * (x * y);
    const float sm5 = -1.0925484305920792f * (y * z);
    const float sm6 =  0.31539156525252005f * (2.0f * zz - xx - yy);
    const float sm7 = -1.0925484305920792f * (x * z);
    const float sm8 =  0.5462742152960396f * (xx - yy);

    const float qx = qp[n * 3 + 0];
    const float qy = qp[n * 3 + 1];
    const float qz = qp[n * 3 + 2];

    // --- neighbor indices (wave-uniform -> SGPR) + inverse-square-dist weights ---
    int   idx[KNN];
    float w[KNN];
    float wsum = 0.0f;
#pragma unroll
    for (int k = 0; k < KNN; ++k) {
        int id = knn[n * KNN + k];
        id = __builtin_amdgcn_readfirstlane(id);   // wave-uniform -> SGPR addressing
        idx[k] = id;
        const float px = cpos[id * 3 + 0];
        const float py = cpos[id * 3 + 1];
        const float pz = cpos[id * 3 + 2];
        const float dx = qx - px, dy = qy - py, dz = qz - pz;
        const float sd = dx * dx + dy * dy + dz * dz + 1e-16f;
        w[k] = 1.0f / sd;                          // 1/sqrt(sd)^2 == 1/sd
        wsum += w[k];
    }
    const float winv = 1.0f / wsum;

    // --- fused gathers + dual einsum ---
    float acc_c = 0.0f;   // query_codes[n][lane]
    float acc_s = 0.0f;   // query_sh_codes[n][lane]
#pragma unroll
    for (int k = 0; k < KNN; ++k) {
        const float wk = w[k] * winv;
        acc_c += wk * codes[(size_t)idx[k] * CDIM + lane];
        const float* p = shc + (size_t)idx[k] * (CDIM * SHB) + lane * SHB;
        float agg = sm0 * p[0] + sm1 * p[1] + sm2 * p[2]
                  + sm3 * p[3] + sm4 * p[4] + sm5 * p[5]
                  + sm6 * p[6] + sm7 * p[7] + sm8 * p[8];
        acc_s += wk * agg;
    }

    out[n * CDIM + lane] = acc_c;
    out[(size_t)NPTS * CDIM + n * CDIM + lane] = acc_s;
}

extern "C" void kernel_launch(void* const* d_in, const int* in_sizes, int n_in,
                              void* d_out, int out_size, void* d_ws, size_t ws_size,
                              hipStream_t stream) {
    const float* qp    = (const float*)d_in[0]; // query_points (1,N,3)
    const float* vd    = (const float*)d_in[1]; // viewdirs (N,3)
    const float* cpos  = (const float*)d_in[2]; // codes_position (1,8192,3)
    const float* codes = (const float*)d_in[3]; // codes (1,8192,64)
    const float* shc   = (const float*)d_in[4]; // sh_codes (1,8192,576)
    // d_in[5] = indices (always 0, batch dim of size 1) -- unused
    const int*   knn   = (const int*)d_in[6];   // knn_idx (N,8)
    float* out = (float*)d_out;

    dim3 grid(NPTS / 4);
    dim3 block(256);
    hipLaunchKernelGGL(shcode_kernel, grid, block, 0, stream,
                       qp, vd, cpos, codes, shc, knn, out);
}

// Round 2
// 77.227 us; speedup vs baseline: 2.0128x; 2.0128x over previous
//
#include <hip/hip_runtime.h>
#include <hip/hip_fp16.h>

#define NPTS   65536
#define KNN    8
#define CDIM   64
#define SHB    9
#define NCODES 8192
#define RECW   5   // __half2 (dwords) per lane per code record

// Record layout: rec[code][j*64 + lane], j=0..4, each a __half2:
//   j=0:(s0,s1) j=1:(s2,s3) j=2:(s4,s5) j=3:(s6,s7) j=4:(s8, codes[code][lane])
// 1280 B/code vs 2560 B gathered in fp32 layout -> 50% gather traffic,
// and each wave load of rec[...][j*64+lane] is one coalesced 256 B burst.

__global__ __launch_bounds__(256) void repack_kernel(
    const float* __restrict__ codes,   // (8192,64)
    const float* __restrict__ shc,     // (8192,576)
    __half2* __restrict__ rec)         // (8192, 5*64)
{
    const int wid  = threadIdx.x >> 6;
    const int lane = threadIdx.x & 63;
    const int c    = blockIdx.x * 4 + wid;   // one wave per code

    const float* p = shc + (size_t)c * (CDIM * SHB) + lane * SHB;
    float v[SHB];
#pragma unroll
    for (int s = 0; s < SHB; ++s) v[s] = p[s];
    const float cv = codes[c * CDIM + lane];

    __half2* r = rec + (size_t)c * (RECW * 64) + lane;
    r[0 * 64] = __floats2half2_rn(v[0], v[1]);
    r[1 * 64] = __floats2half2_rn(v[2], v[3]);
    r[2 * 64] = __floats2half2_rn(v[4], v[5]);
    r[3 * 64] = __floats2half2_rn(v[6], v[7]);
    r[4 * 64] = __floats2half2_rn(v[8], cv);
}

__global__ __launch_bounds__(256) void shcode_fp16_kernel(
    const float* __restrict__ qp,
    const float* __restrict__ vd,
    const float* __restrict__ cpos,
    const __half2* __restrict__ rec,
    const int*   __restrict__ knn,
    float* __restrict__ out)
{
    const int wid  = threadIdx.x >> 6;
    const int lane = threadIdx.x & 63;
    const int n    = blockIdx.x * 4 + wid;

    // --- neighbor indices (wave-uniform -> SGPR) ---
    int idx[KNN];
#pragma unroll
    for (int k = 0; k < KNN; ++k)
        idx[k] = __builtin_amdgcn_readfirstlane(knn[n * KNN + k]);

    // --- issue ALL gather loads first (max memory-level parallelism) ---
    __half2 raw[KNN][RECW];
#pragma unroll
    for (int k = 0; k < KNN; ++k) {
        const __half2* r = rec + (size_t)idx[k] * (RECW * 64) + lane;
#pragma unroll
        for (int j = 0; j < RECW; ++j) raw[k][j] = r[j * 64];
    }

    // --- SH basis (wave-uniform broadcast loads) ---
    const float x = vd[n * 3 + 0];
    const float y = vd[n * 3 + 1];
    const float z = vd[n * 3 + 2];
    const float xx = x * x, yy = y * y, zz = z * z;
    const float sm0 = 0.28209479177387814f;
    const float sm1 = -0.4886025119029199f * y;
    const float sm2 =  0.4886025119029199f * z;
    const float sm3 = -0.4886025119029199f * x;
    const float sm4 =  1.0925484305920792f * (x * y);
    const float sm5 = -1.0925484305920792f * (y * z);
    const float sm6 =  0.31539156525252005f * (2.0f * zz - xx - yy);
    const float sm7 = -1.0925484305920792f * (x * z);
    const float sm8 =  0.5462742152960396f * (xx - yy);

    const float qx = qp[n * 3 + 0];
    const float qy = qp[n * 3 + 1];
    const float qz = qp[n * 3 + 2];

    // --- inverse-square-dist weights ---
    float w[KNN];
    float wsum = 0.0f;
#pragma unroll
    for (int k = 0; k < KNN; ++k) {
        const int id = idx[k];
        const float dx = qx - cpos[id * 3 + 0];
        const float dy = qy - cpos[id * 3 + 1];
        const float dz = qz - cpos[id * 3 + 2];
        const float sd = dx * dx + dy * dy + dz * dz + 1e-16f;
        w[k] = 1.0f / sd;
        wsum += w[k];
    }
    const float winv = 1.0f / wsum;

    // --- consume gathers ---
    float acc_c = 0.0f;
    float acc_s = 0.0f;
#pragma unroll
    for (int k = 0; k < KNN; ++k) {
        const float wk = w[k] * winv;
        const float2 f0 = __half22float2(raw[k][0]);
        const float2 f1 = __half22float2(raw[k][1]);
        const float2 f2 = __half22float2(raw[k][2]);
        const float2 f3 = __half22float2(raw[k][3]);
        const float2 f4 = __half22float2(raw[k][4]);
        float agg = sm0 * f0.x + sm1 * f0.y + sm2 * f1.x
                  + sm3 * f1.y + sm4 * f2.x + sm5 * f2.y
                  + sm6 * f3.x + sm7 * f3.y + sm8 * f4.x;
        acc_s += wk * agg;
        acc_c += wk * f4.y;
    }

    out[n * CDIM + lane] = acc_c;
    out[(size_t)NPTS * CDIM + n * CDIM + lane] = acc_s;
}

// --- fallback (round-1 fp32 direct-gather kernel) if workspace too small ---
__global__ __launch_bounds__(256) void shcode_kernel(
    const float* __restrict__ qp, const float* __restrict__ vd,
    const float* __restrict__ cpos, const float* __restrict__ codes,
    const float* __restrict__ shc, const int* __restrict__ knn,
    float* __restrict__ out)
{
    const int wid  = threadIdx.x >> 6;
    const int lane = threadIdx.x & 63;
    const int n    = blockIdx.x * 4 + wid;

    const float x = vd[n * 3 + 0], y = vd[n * 3 + 1], z = vd[n * 3 + 2];
    const float xx = x * x, yy = y * y, zz = z * z;
    const float sm0 = 0.28209479177387814f;
    const float sm1 = -0.4886025119029199f * y;
    const float sm2 =  0.4886025119029199f * z;
    const float sm3 = -0.4886025119029199f * x;
    const float sm4 =  1.0925484305920792f * (x * y);
    const float sm5 = -1.0925484305920792f * (y * z);
    const float sm6 =  0.31539156525252005f * (2.0f * zz - xx - yy);
    const float sm7 = -1.0925484305920792f * (x * z);
    const float sm8 =  0.5462742152960396f * (xx - yy);

    const float qx = qp[n * 3 + 0], qy = qp[n * 3 + 1], qz = qp[n * 3 + 2];

    int idx[KNN]; float w[KNN]; float wsum = 0.0f;
#pragma unroll
    for (int k = 0; k < KNN; ++k) {
        int id = __builtin_amdgcn_readfirstlane(knn[n * KNN + k]);
        idx[k] = id;
        const float dx = qx - cpos[id * 3 + 0];
        const float dy = qy - cpos[id * 3 + 1];
        const float dz = qz - cpos[id * 3 + 2];
        const float sd = dx * dx + dy * dy + dz * dz + 1e-16f;
        w[k] = 1.0f / sd; wsum += w[k];
    }
    const float winv = 1.0f / wsum;

    float acc_c = 0.0f, acc_s = 0.0f;
#pragma unroll
    for (int k = 0; k < KNN; ++k) {
        const float wk = w[k] * winv;
        acc_c += wk * codes[(size_t)idx[k] * CDIM + lane];
        const float* p = shc + (size_t)idx[k] * (CDIM * SHB) + lane * SHB;
        acc_s += wk * (sm0 * p[0] + sm1 * p[1] + sm2 * p[2]
                     + sm3 * p[3] + sm4 * p[4] + sm5 * p[5]
                     + sm6 * p[6] + sm7 * p[7] + sm8 * p[8]);
    }
    out[n * CDIM + lane] = acc_c;
    out[(size_t)NPTS * CDIM + n * CDIM + lane] = acc_s;
}

extern "C" void kernel_launch(void* const* d_in, const int* in_sizes, int n_in,
                              void* d_out, int out_size, void* d_ws, size_t ws_size,
                              hipStream_t stream) {
    const float* qp    = (const float*)d_in[0];
    const float* vd    = (const float*)d_in[1];
    const float* cpos  = (const float*)d_in[2];
    const float* codes = (const float*)d_in[3];
    const float* shc   = (const float*)d_in[4];
    const int*   knn   = (const int*)d_in[6];
    float* out = (float*)d_out;

    const size_t rec_bytes = (size_t)NCODES * RECW * 64 * sizeof(__half2); // 10.5 MB

    if (ws_size >= rec_bytes) {
        __half2* rec = (__half2*)d_ws;
        hipLaunchKernelGGL(repack_kernel, dim3(NCODES / 4), dim3(256), 0, stream,
                           codes, shc, rec);
        hipLaunchKernelGGL(shcode_fp16_kernel, dim3(NPTS / 4), dim3(256), 0, stream,
                           qp, vd, cpos, rec, knn, out);
    } else {
        hipLaunchKernelGGL(shcode_kernel, dim3(NPTS / 4), dim3(256), 0, stream,
                           qp, vd, cpos, codes, shc, knn, out);
    }
}